// Round 9
// baseline (820.399 us; speedup 1.0000x reference)
//
#include <hip/hip_runtime.h>
#include <hip/hip_bf16.h>

#define N_NODES 2000
#define N_EDGES 32000

// ---------------- CSR build ----------------
__global__ __launch_bounds__(256) void k_hist(const int* __restrict__ dst, int* __restrict__ cnt) {
    int e = blockIdx.x * 256 + threadIdx.x;
    if (e < N_EDGES) atomicAdd(&cnt[dst[e]], 1);
}

__global__ __launch_bounds__(1024) void k_scan(const int* __restrict__ cnt, int* __restrict__ rowptr) {
    __shared__ int buf[2][2048];
    const int t = threadIdx.x;
    for (int i = t; i < 2048; i += 1024) buf[0][i] = (i < N_NODES) ? cnt[i] : 0;
    __syncthreads();
    int cur = 0;
    for (int off = 1; off < 2048; off <<= 1) {
        for (int i = t; i < 2048; i += 1024) {
            int v = buf[cur][i];
            if (i >= off) v += buf[cur][i - off];
            buf[cur ^ 1][i] = v;
        }
        __syncthreads();
        cur ^= 1;
    }
    for (int i = t; i < N_NODES; i += 1024) rowptr[i + 1] = buf[cur][i];
    if (t == 0) rowptr[0] = 0;
}

__global__ __launch_bounds__(256) void k_scatter(const int* __restrict__ src, const int* __restrict__ dst,
                                                 const int* __restrict__ rowptr, int* __restrict__ fill,
                                                 int* __restrict__ col) {
    int e = blockIdx.x * 256 + threadIdx.x;
    if (e < N_EDGES) {
        int d = dst[e];
        int pos = atomicAdd(&fill[d], 1);
        col[rowptr[d] + pos] = src[e];
    }
}

// ---------------- weight repack: [Cout][Cin][3][3] (x2) -> [s][cin*9+k][Cout] ----------------
__global__ __launch_bounds__(256) void k_pack(const float* __restrict__ wself, const float* __restrict__ wneigh,
                                              float* __restrict__ wp, int Cout, int Cin) {
    int idx = blockIdx.x * 256 + threadIdx.x;
    int total = Cout * Cin * 9;
    if (idx >= total) return;
    int c = idx / (Cin * 9);
    int rem = idx % (Cin * 9);   // cin*9 + k
    wp[(0 * Cin * 9 + rem) * Cout + c] = wself[idx];
    wp[(1 * Cin * 9 + rem) * Cout + c] = wneigh[idx];
}

// ---------------- mean aggregation over in-neighbors (gather via CSR) ----------------
template <int F>
__global__ __launch_bounds__(256) void k_agg(const float* __restrict__ feat, const int* __restrict__ rowptr,
                                             const int* __restrict__ col, float* __restrict__ out) {
    const int node = blockIdx.x;
    const int t = threadIdx.x;
    const int beg = rowptr[node], end = rowptr[node + 1];
    const int deg = end - beg;
    const float inv = 1.0f / (float)(deg > 1 ? deg : 1);
    __shared__ int nb[256];
    if (deg <= 256) {
        if (t < deg) nb[t] = col[beg + t];
        __syncthreads();
        for (int slot = t; slot < F / 4; slot += 256) {
            const int e = 4 * slot;
            float4 a0 = {0.f, 0.f, 0.f, 0.f}, a1 = {0.f, 0.f, 0.f, 0.f};
            int j = 0;
            for (; j + 1 < deg; j += 2) {
                const float4 v0 = *reinterpret_cast<const float4*>(feat + (size_t)nb[j] * F + e);
                const float4 v1 = *reinterpret_cast<const float4*>(feat + (size_t)nb[j + 1] * F + e);
                a0.x += v0.x; a0.y += v0.y; a0.z += v0.z; a0.w += v0.w;
                a1.x += v1.x; a1.y += v1.y; a1.z += v1.z; a1.w += v1.w;
            }
            if (j < deg) {
                const float4 v0 = *reinterpret_cast<const float4*>(feat + (size_t)nb[j] * F + e);
                a0.x += v0.x; a0.y += v0.y; a0.z += v0.z; a0.w += v0.w;
            }
            float4 r = {(a0.x + a1.x) * inv, (a0.y + a1.y) * inv, (a0.z + a1.z) * inv, (a0.w + a1.w) * inv};
            *reinterpret_cast<float4*>(out + (size_t)node * F + e) = r;
        }
        return;
    }
    for (int base = 0; base < F; base += 1024) {
        float4 a = {0.f, 0.f, 0.f, 0.f};
        const int e = base + 4 * t;
        const bool act = (e < F);
        for (int jb = beg; jb < end; jb += 256) {
            int cnt2 = min(end - jb, 256);
            __syncthreads();
            if (t < cnt2) nb[t] = col[jb + t];
            __syncthreads();
            if (act) {
                for (int j = 0; j < cnt2; ++j) {
                    const float4 v = *reinterpret_cast<const float4*>(feat + (size_t)nb[j] * F + e);
                    a.x += v.x; a.y += v.y; a.z += v.z; a.w += v.w;
                }
            }
        }
        if (act) {
            float4 r = {a.x * inv, a.y * inv, a.z * inv, a.w * inv};
            *reinterpret_cast<float4*>(out + (size_t)node * F + e) = r;
        }
    }
}

// ---------------- conv1: Cin=1, Cout=32, 32x32 -> conv 30x30 -> relu+pool 15x15 ----------------
__global__ __launch_bounds__(256) void k_conv1(const float* __restrict__ x, const float* __restrict__ xagg,
                                               const float* __restrict__ w1s, const float* __restrict__ w1n,
                                               float* __restrict__ h1) {
    const int node = blockIdx.x;
    const int t = threadIdx.x;
    __shared__ __align__(16) float xs[1024];
    __shared__ __align__(16) float xa[1024];
    __shared__ __align__(16) float wl[9 * 2 * 32];   // [(k*2+s)*32 + c]
    {
        const float4* xsrc = reinterpret_cast<const float4*>(x + (size_t)node * 1024);
        const float4* asrc = reinterpret_cast<const float4*>(xagg + (size_t)node * 1024);
        reinterpret_cast<float4*>(xs)[t] = xsrc[t];
        reinterpret_cast<float4*>(xa)[t] = asrc[t];
        for (int i = t; i < 576; i += 256) {
            int s = i / 288, rem = i % 288;  // rem = c*9+k
            int c = rem / 9, k = rem % 9;
            wl[(k * 2 + s) * 32 + c] = (s ? w1n : w1s)[rem];
        }
    }
    __syncthreads();
    const int g = t >> 5;    // 8 groups of 4 cout
    const int p = t & 31;
    for (int r = p; r < 225; r += 32) {
        const int py = r / 15, px = r % 15;
        const int oy = 2 * py, ox = 2 * px;
        float acc[4][4];
#pragma unroll
        for (int d = 0; d < 4; ++d)
#pragma unroll
            for (int j = 0; j < 4; ++j) acc[d][j] = 0.f;
#pragma unroll
        for (int ky = 0; ky < 3; ++ky)
#pragma unroll
            for (int kx = 0; kx < 3; ++kx) {
                const int k = ky * 3 + kx;
                const float xv[4] = {xs[(oy + ky) * 32 + ox + kx],     xs[(oy + ky) * 32 + ox + kx + 1],
                                     xs[(oy + ky + 1) * 32 + ox + kx], xs[(oy + ky + 1) * 32 + ox + kx + 1]};
                const float av[4] = {xa[(oy + ky) * 32 + ox + kx],     xa[(oy + ky) * 32 + ox + kx + 1],
                                     xa[(oy + ky + 1) * 32 + ox + kx], xa[(oy + ky + 1) * 32 + ox + kx + 1]};
                const float4 wS = *reinterpret_cast<const float4*>(&wl[(k * 2 + 0) * 32 + g * 4]);
                const float4 wN = *reinterpret_cast<const float4*>(&wl[(k * 2 + 1) * 32 + g * 4]);
                const float wSa[4] = {wS.x, wS.y, wS.z, wS.w};
                const float wNa[4] = {wN.x, wN.y, wN.z, wN.w};
#pragma unroll
                for (int d = 0; d < 4; ++d)
#pragma unroll
                    for (int j = 0; j < 4; ++j) acc[d][j] += xv[d] * wSa[j] + av[d] * wNa[j];
            }
#pragma unroll
        for (int j = 0; j < 4; ++j) {
            float m = fmaxf(fmaxf(acc[0][j], acc[1][j]), fmaxf(acc[2][j], acc[3][j]));
            m = fmaxf(m, 0.f);
            h1[(size_t)node * 7200 + (size_t)(g * 4 + j) * 225 + r] = m;
        }
    }
}

// ---------------- conv2: Cin=32, Cout=64, 15x15 -> conv 13x13 -> relu+pool 6x6 ----------------
// 16-cin chunked staging (18.4 KB LDS -> ~7 blocks/CU for TLP) + cin unroll-2 for ILP.
// Stride-19 LDS planes (max 3-way bank aliasing on patch reads).
__global__ __launch_bounds__(288, 4) void k_conv2(const float* __restrict__ h1, const float* __restrict__ agg,
                                                  const float* __restrict__ wp, float* __restrict__ h2) {
    const int node = blockIdx.x;
    const int t = threadIdx.x;
    __shared__ float xs[16 * 288];   // [cin_local][y*19 + x], 18.4 KB
    const int p = t % 36, g = t / 36;    // 36 pooled positions, 8 groups of 8 cout
    const int py = p / 6, px = p % 6;
    const int oy = 2 * py, ox = 2 * px;
    float acc[4][8];
#pragma unroll
    for (int d = 0; d < 4; ++d)
#pragma unroll
        for (int c = 0; c < 8; ++c) acc[d][c] = 0.f;

    const float* srcs0 = h1 + (size_t)node * 7200;
    const float* srcs1 = agg + (size_t)node * 7200;
#pragma unroll 1
    for (int pass = 0; pass < 2; ++pass) {
        const float4* S4 = reinterpret_cast<const float4*>(pass ? srcs1 : srcs0);
        const float* wpp = wp + (size_t)pass * (32 * 9 * 64);
#pragma unroll 1
        for (int chunk = 0; chunk < 2; ++chunk) {
            __syncthreads();   // previous chunk compute done before overwrite
            // stage 16 cin planes: 900 float4, coalesced, scatter to stride-19
#pragma unroll 1
            for (int i = t; i < 900; i += 288) {
                const float4 v = S4[900 * chunk + i];
                const float va[4] = {v.x, v.y, v.z, v.w};
                const int f0 = 4 * i;
#pragma unroll
                for (int j = 0; j < 4; ++j) {
                    const int idx = f0 + j;
                    const int cl = idx / 225, rem = idx % 225;
                    const int y = rem / 15, x = rem % 15;
                    xs[cl * 288 + y * 19 + x] = va[j];
                }
            }
            __syncthreads();
            const float* wchunk = wpp + (size_t)(16 * chunk) * 9 * 64;
#pragma unroll 2
            for (int cl = 0; cl < 16; ++cl) {
                float pt[4][4];
                const float* xb = xs + cl * 288 + oy * 19 + ox;
#pragma unroll
                for (int r = 0; r < 4; ++r)
#pragma unroll
                    for (int c = 0; c < 4; ++c) pt[r][c] = xb[r * 19 + c];
                const float* wrow = wchunk + (size_t)cl * 9 * 64 + g * 8;
#pragma unroll
                for (int ky = 0; ky < 3; ++ky)
#pragma unroll
                    for (int kx = 0; kx < 3; ++kx) {
                        const int k = ky * 3 + kx;
                        const float4 w0 = *reinterpret_cast<const float4*>(wrow + k * 64);
                        const float4 w1 = *reinterpret_cast<const float4*>(wrow + k * 64 + 4);
                        const float wa[8] = {w0.x, w0.y, w0.z, w0.w, w1.x, w1.y, w1.z, w1.w};
#pragma unroll
                        for (int dy = 0; dy < 2; ++dy)
#pragma unroll
                            for (int dx = 0; dx < 2; ++dx)
#pragma unroll
                                for (int c = 0; c < 8; ++c)
                                    acc[dy * 2 + dx][c] += pt[dy + ky][dx + kx] * wa[c];
                    }
            }
        }
    }
#pragma unroll
    for (int c = 0; c < 8; ++c) {
        float m = fmaxf(fmaxf(acc[0][c], acc[1][c]), fmaxf(acc[2][c], acc[3][c]));
        m = fmaxf(m, 0.f);
        h2[(size_t)node * 2304 + (size_t)(g * 8 + c) * 36 + p] = m;
    }
}

// ---------------- conv3: Cin=64, Cout=128, 6x6 -> conv 4x4 -> relu+pool 2x2 ----------------
__global__ __launch_bounds__(128, 4) void k_conv3(const float* __restrict__ h2, const float* __restrict__ agg,
                                                  const float* __restrict__ wp, float* __restrict__ out) {
    const int node = blockIdx.x;
    const int t = threadIdx.x;
    __shared__ __align__(16) float xs[2304];
    const int p = t & 3, g = t >> 2;   // 4 pooled positions, 32 groups of 4 cout
    const int PY = p >> 1, PX = p & 1;
    const int oy = 2 * PY, ox = 2 * PX;
    float acc[4][4];
#pragma unroll
    for (int d = 0; d < 4; ++d)
#pragma unroll
        for (int c = 0; c < 4; ++c) acc[d][c] = 0.f;

    const float* srcs0 = h2 + (size_t)node * 2304;
    const float* srcs1 = agg + (size_t)node * 2304;
#pragma unroll 1
    for (int pass = 0; pass < 2; ++pass) {
        const float4* s1 = reinterpret_cast<const float4*>(pass ? srcs1 : srcs0);
        float4* d1 = reinterpret_cast<float4*>(xs);
        __syncthreads();
        for (int i = t; i < 576; i += 128) d1[i] = s1[i];
        __syncthreads();
        const float* wpp = wp + (size_t)pass * (64 * 9 * 128);
#pragma unroll 2
        for (int cin = 0; cin < 64; ++cin) {
            float pt[4][4];
            const float* xb = xs + cin * 36 + oy * 6 + ox;
#pragma unroll
            for (int r = 0; r < 4; ++r)
#pragma unroll
                for (int c = 0; c < 4; ++c) pt[r][c] = xb[r * 6 + c];
            const float* wrow = wpp + (size_t)cin * 9 * 128 + g * 4;
#pragma unroll
            for (int ky = 0; ky < 3; ++ky)
#pragma unroll
                for (int kx = 0; kx < 3; ++kx) {
                    const float4 w0 = *reinterpret_cast<const float4*>(wrow + (ky * 3 + kx) * 128);
                    const float wa[4] = {w0.x, w0.y, w0.z, w0.w};
#pragma unroll
                    for (int dy = 0; dy < 2; ++dy)
#pragma unroll
                        for (int dx = 0; dx < 2; ++dx)
#pragma unroll
                            for (int c = 0; c < 4; ++c)
                                acc[dy * 2 + dx][c] += pt[dy + ky][dx + kx] * wa[c];
                }
        }
    }
#pragma unroll
    for (int c = 0; c < 4; ++c) {
        float m = fmaxf(fmaxf(acc[0][c], acc[1][c]), fmaxf(acc[2][c], acc[3][c]));
        m = fmaxf(m, 0.f);
        out[(size_t)node * 512 + (size_t)(g * 4 + c) * 4 + PY * 2 + PX] = m;
    }
}

// ---------------- launcher ----------------
extern "C" void kernel_launch(void* const* d_in, const int* in_sizes, int n_in,
                              void* d_out, int out_size, void* d_ws, size_t ws_size,
                              hipStream_t stream) {
    (void)in_sizes; (void)n_in; (void)out_size; (void)ws_size;
    const float* in_feat = (const float*)d_in[0];
    const float* w1s = (const float*)d_in[1];
    const float* w1n = (const float*)d_in[2];
    const float* w2s = (const float*)d_in[3];
    const float* w2n = (const float*)d_in[4];
    const float* w3s = (const float*)d_in[5];
    const float* w3n = (const float*)d_in[6];
    const int* srcp = (const int*)d_in[7];
    const int* dstp = (const int*)d_in[8];
    float* outp = (float*)d_out;

    char* w = (char*)d_ws;
    size_t off = 0;
    auto alloc = [&](size_t bytes) { void* p = w + off; off += (bytes + 255) & ~(size_t)255; return p; };
    int* cnt    = (int*)alloc(N_NODES * sizeof(int));
    int* rowptr = (int*)alloc((N_NODES + 1) * sizeof(int));
    int* fill   = (int*)alloc(N_NODES * sizeof(int));
    int* col    = (int*)alloc(N_EDGES * sizeof(int));
    float* w2p  = (float*)alloc((size_t)64 * 32 * 9 * 2 * sizeof(float));
    float* w3p  = (float*)alloc((size_t)128 * 64 * 9 * 2 * sizeof(float));
    float* agg1 = (float*)alloc((size_t)N_NODES * 1024 * sizeof(float));
    float* h1   = (float*)alloc((size_t)N_NODES * 7200 * sizeof(float));
    float* agg2 = (float*)alloc((size_t)N_NODES * 7200 * sizeof(float));
    float* h2   = (float*)alloc((size_t)N_NODES * 2304 * sizeof(float));
    float* agg3 = (float*)alloc((size_t)N_NODES * 2304 * sizeof(float));

    hipMemsetAsync(cnt, 0, N_NODES * sizeof(int), stream);
    hipMemsetAsync(fill, 0, N_NODES * sizeof(int), stream);

    k_hist<<<(N_EDGES + 255) / 256, 256, 0, stream>>>(dstp, cnt);
    k_scan<<<1, 1024, 0, stream>>>(cnt, rowptr);
    k_scatter<<<(N_EDGES + 255) / 256, 256, 0, stream>>>(srcp, dstp, rowptr, fill, col);
    k_pack<<<(64 * 32 * 9 + 255) / 256, 256, 0, stream>>>(w2s, w2n, w2p, 64, 32);
    k_pack<<<(128 * 64 * 9 + 255) / 256, 256, 0, stream>>>(w3s, w3n, w3p, 128, 64);

    // layer 1
    k_agg<1024><<<N_NODES, 256, 0, stream>>>(in_feat, rowptr, col, agg1);
    k_conv1<<<N_NODES, 256, 0, stream>>>(in_feat, agg1, w1s, w1n, h1);
    // layer 2
    k_agg<7200><<<N_NODES, 256, 0, stream>>>(h1, rowptr, col, agg2);
    k_conv2<<<N_NODES, 288, 0, stream>>>(h1, agg2, w2p, h2);
    // layer 3
    k_agg<2304><<<N_NODES, 256, 0, stream>>>(h2, rowptr, col, agg3);
    k_conv3<<<N_NODES, 128, 0, stream>>>(h2, agg3, w3p, outp);
}

// Round 10
// 450.967 us; speedup vs baseline: 1.8192x; 1.8192x over previous
//
#include <hip/hip_runtime.h>
#include <hip/hip_bf16.h>

#define N_NODES 2000
#define N_EDGES 32000

typedef __attribute__((ext_vector_type(8))) short v8s;
typedef __attribute__((ext_vector_type(4))) float v4f;

__device__ __forceinline__ unsigned short bf16_rne(float x) {
    unsigned u = __float_as_uint(x);
    unsigned r = (u + 0x7fffu + ((u >> 16) & 1u)) >> 16;
    return (unsigned short)r;
}
__device__ __forceinline__ float bf16_to_f(unsigned short h) {
    return __uint_as_float(((unsigned)h) << 16);
}

// ---------------- CSR build ----------------
__global__ __launch_bounds__(256) void k_hist(const int* __restrict__ dst, int* __restrict__ cnt) {
    int e = blockIdx.x * 256 + threadIdx.x;
    if (e < N_EDGES) atomicAdd(&cnt[dst[e]], 1);
}

__global__ __launch_bounds__(1024) void k_scan(const int* __restrict__ cnt, int* __restrict__ rowptr) {
    __shared__ int buf[2][2048];
    const int t = threadIdx.x;
    for (int i = t; i < 2048; i += 1024) buf[0][i] = (i < N_NODES) ? cnt[i] : 0;
    __syncthreads();
    int cur = 0;
    for (int off = 1; off < 2048; off <<= 1) {
        for (int i = t; i < 2048; i += 1024) {
            int v = buf[cur][i];
            if (i >= off) v += buf[cur][i - off];
            buf[cur ^ 1][i] = v;
        }
        __syncthreads();
        cur ^= 1;
    }
    for (int i = t; i < N_NODES; i += 1024) rowptr[i + 1] = buf[cur][i];
    if (t == 0) rowptr[0] = 0;
}

__global__ __launch_bounds__(256) void k_scatter(const int* __restrict__ src, const int* __restrict__ dst,
                                                 const int* __restrict__ rowptr, int* __restrict__ fill,
                                                 int* __restrict__ col) {
    int e = blockIdx.x * 256 + threadIdx.x;
    if (e < N_EDGES) {
        int d = dst[e];
        int pos = atomicAdd(&fill[d], 1);
        col[rowptr[d] + pos] = src[e];
    }
}

// ---------------- weight split+pack for MFMA fragments ----------------
// conv2: [pass2][shift9][mtile4][lane64][8] ; cout=i*16+(l&15), cin=(l>>4)*8+j
__global__ __launch_bounds__(256) void k_pack2(const float* __restrict__ ws, const float* __restrict__ wn,
                                               unsigned short* __restrict__ whi, unsigned short* __restrict__ wlo) {
    int x = blockIdx.x * 256 + threadIdx.x;
    if (x >= 36864) return;
    int j = x & 7, l = (x >> 3) & 63, i = (x >> 9) & 3, k = (x >> 11) % 9, s = x / 18432;
    int cout = i * 16 + (l & 15), cin = (l >> 4) * 8 + j;
    float w = (s ? wn : ws)[(cout * 32 + cin) * 9 + k];
    unsigned short h = bf16_rne(w);
    whi[x] = h;
    wlo[x] = bf16_rne(w - bf16_to_f(h));
}

// conv3: [pass2][shift9][kstep2][mtile8][lane64][8] ; cout=i*16+(l&15), cin=ks*32+(l>>4)*8+j
__global__ __launch_bounds__(256) void k_pack3(const float* __restrict__ ws, const float* __restrict__ wn,
                                               unsigned short* __restrict__ whi, unsigned short* __restrict__ wlo) {
    int x = blockIdx.x * 256 + threadIdx.x;
    if (x >= 147456) return;
    int j = x & 7, l = (x >> 3) & 63, i = (x >> 9) & 7, ks = (x >> 12) & 1, k = (x >> 13) % 9, s = x / 73728;
    int cout = i * 16 + (l & 15), cin = ks * 32 + (l >> 4) * 8 + j;
    float w = (s ? wn : ws)[(cout * 64 + cin) * 9 + k];
    unsigned short h = bf16_rne(w);
    whi[x] = h;
    wlo[x] = bf16_rne(w - bf16_to_f(h));
}

// ---------------- mean aggregation over in-neighbors (gather via CSR) ----------------
template <int F>
__global__ __launch_bounds__(256) void k_agg(const float* __restrict__ feat, const int* __restrict__ rowptr,
                                             const int* __restrict__ col, float* __restrict__ out) {
    const int node = blockIdx.x;
    const int t = threadIdx.x;
    const int beg = rowptr[node], end = rowptr[node + 1];
    const int deg = end - beg;
    const float inv = 1.0f / (float)(deg > 1 ? deg : 1);
    __shared__ int nb[256];
    if (deg <= 256) {
        if (t < deg) nb[t] = col[beg + t];
        __syncthreads();
        for (int slot = t; slot < F / 4; slot += 256) {
            const int e = 4 * slot;
            float4 a0 = {0.f, 0.f, 0.f, 0.f}, a1 = {0.f, 0.f, 0.f, 0.f};
            int j = 0;
            for (; j + 1 < deg; j += 2) {
                const float4 v0 = *reinterpret_cast<const float4*>(feat + (size_t)nb[j] * F + e);
                const float4 v1 = *reinterpret_cast<const float4*>(feat + (size_t)nb[j + 1] * F + e);
                a0.x += v0.x; a0.y += v0.y; a0.z += v0.z; a0.w += v0.w;
                a1.x += v1.x; a1.y += v1.y; a1.z += v1.z; a1.w += v1.w;
            }
            if (j < deg) {
                const float4 v0 = *reinterpret_cast<const float4*>(feat + (size_t)nb[j] * F + e);
                a0.x += v0.x; a0.y += v0.y; a0.z += v0.z; a0.w += v0.w;
            }
            float4 r = {(a0.x + a1.x) * inv, (a0.y + a1.y) * inv, (a0.z + a1.z) * inv, (a0.w + a1.w) * inv};
            *reinterpret_cast<float4*>(out + (size_t)node * F + e) = r;
        }
        return;
    }
    for (int base = 0; base < F; base += 1024) {
        float4 a = {0.f, 0.f, 0.f, 0.f};
        const int e = base + 4 * t;
        const bool act = (e < F);
        for (int jb = beg; jb < end; jb += 256) {
            int cnt2 = min(end - jb, 256);
            __syncthreads();
            if (t < cnt2) nb[t] = col[jb + t];
            __syncthreads();
            if (act) {
                for (int j = 0; j < cnt2; ++j) {
                    const float4 v = *reinterpret_cast<const float4*>(feat + (size_t)nb[j] * F + e);
                    a.x += v.x; a.y += v.y; a.z += v.z; a.w += v.w;
                }
            }
        }
        if (act) {
            float4 r = {a.x * inv, a.y * inv, a.z * inv, a.w * inv};
            *reinterpret_cast<float4*>(out + (size_t)node * F + e) = r;
        }
    }
}

// ---------------- conv1: Cin=1, Cout=32 (VALU path, small FLOPs) ----------------
__global__ __launch_bounds__(256) void k_conv1(const float* __restrict__ x, const float* __restrict__ xagg,
                                               const float* __restrict__ w1s, const float* __restrict__ w1n,
                                               float* __restrict__ h1) {
    const int node = blockIdx.x;
    const int t = threadIdx.x;
    __shared__ __align__(16) float xs[1024];
    __shared__ __align__(16) float xa[1024];
    __shared__ __align__(16) float wl[9 * 2 * 32];
    {
        const float4* xsrc = reinterpret_cast<const float4*>(x + (size_t)node * 1024);
        const float4* asrc = reinterpret_cast<const float4*>(xagg + (size_t)node * 1024);
        reinterpret_cast<float4*>(xs)[t] = xsrc[t];
        reinterpret_cast<float4*>(xa)[t] = asrc[t];
        for (int i = t; i < 576; i += 256) {
            int s = i / 288, rem = i % 288;
            int c = rem / 9, k = rem % 9;
            wl[(k * 2 + s) * 32 + c] = (s ? w1n : w1s)[rem];
        }
    }
    __syncthreads();
    const int g = t >> 5;
    const int p = t & 31;
    for (int r = p; r < 225; r += 32) {
        const int py = r / 15, px = r % 15;
        const int oy = 2 * py, ox = 2 * px;
        float acc[4][4];
#pragma unroll
        for (int d = 0; d < 4; ++d)
#pragma unroll
            for (int j = 0; j < 4; ++j) acc[d][j] = 0.f;
#pragma unroll
        for (int ky = 0; ky < 3; ++ky)
#pragma unroll
            for (int kx = 0; kx < 3; ++kx) {
                const int k = ky * 3 + kx;
                const float xv[4] = {xs[(oy + ky) * 32 + ox + kx],     xs[(oy + ky) * 32 + ox + kx + 1],
                                     xs[(oy + ky + 1) * 32 + ox + kx], xs[(oy + ky + 1) * 32 + ox + kx + 1]};
                const float av[4] = {xa[(oy + ky) * 32 + ox + kx],     xa[(oy + ky) * 32 + ox + kx + 1],
                                     xa[(oy + ky + 1) * 32 + ox + kx], xa[(oy + ky + 1) * 32 + ox + kx + 1]};
                const float4 wS = *reinterpret_cast<const float4*>(&wl[(k * 2 + 0) * 32 + g * 4]);
                const float4 wN = *reinterpret_cast<const float4*>(&wl[(k * 2 + 1) * 32 + g * 4]);
                const float wSa[4] = {wS.x, wS.y, wS.z, wS.w};
                const float wNa[4] = {wN.x, wN.y, wN.z, wN.w};
#pragma unroll
                for (int d = 0; d < 4; ++d)
#pragma unroll
                    for (int j = 0; j < 4; ++j) acc[d][j] += xv[d] * wSa[j] + av[d] * wNa[j];
            }
#pragma unroll
        for (int j = 0; j < 4; ++j) {
            float m = fmaxf(fmaxf(acc[0][j], acc[1][j]), fmaxf(acc[2][j], acc[3][j]));
            m = fmaxf(m, 0.f);
            h1[(size_t)node * 7200 + (size_t)(g * 4 + j) * 225 + r] = m;
        }
    }
}

// ---------------- conv2 (MFMA): Cin=32, Cout=64, 15x15 -> 13x13 -> relu+pool 6x6 ----------------
// Split-bf16 (hi/lo) implicit GEMM: 9 shift-GEMMs of K=32 per pass; X in LDS as [pos225][cin32]
// bf16 hi/lo; B-frag = ds_read_b128 (8 consecutive cin); W-frags prepacked in global (coalesced).
// 9 waves = 9 n-tiles (16 positions of the 12x12 conv grid); 4 m-tiles (64 cout) per wave.
__global__ __launch_bounds__(576, 2) void k_conv2(const float* __restrict__ h1, const float* __restrict__ agg,
                                                  const unsigned short* __restrict__ whi,
                                                  const unsigned short* __restrict__ wlo,
                                                  float* __restrict__ h2) {
    const int node = blockIdx.x;
    const int t = threadIdx.x;
    __shared__ __align__(16) char smem[36864];
    unsigned short* sh = (unsigned short*)smem;            // hi: [225][32] bf16, 14400 B
    unsigned short* sl = (unsigned short*)(smem + 14400);  // lo: same, 14400 B
    float* scb = (float*)smem;                             // epilogue C-buffer [64][144] f32 (reuse)

    const int l = t & 63;
    const int w = t >> 6;           // wave 0..8 = n-tile
    const int p = w * 16 + (l & 15);  // conv position 0..143 on 12x12 grid
    const int oy = p / 12, ox = p % 12;
    const int koff = (l >> 4) * 8;  // cin slice within K=32

    const v4f vzero = {0.f, 0.f, 0.f, 0.f};
    v4f acc[4] = {vzero, vzero, vzero, vzero};

    const float* srcs0 = h1 + (size_t)node * 7200;
    const float* srcs1 = agg + (size_t)node * 7200;
    const v8s* WH = (const v8s*)whi;
    const v8s* WL = (const v8s*)wlo;

#pragma unroll 1
    for (int pass = 0; pass < 2; ++pass) {
        const float* S = pass ? srcs1 : srcs0;
        __syncthreads();   // previous pass compute done before restage
        // stage: [cin][225] fp32 global -> [pos][cin] bf16 hi/lo in LDS
#pragma unroll 1
        for (int ii = t; ii < 900; ii += 576) {
            const int pos = ii % 225, oct = ii / 225;
            const float* sp = S + (oct * 8) * 225 + pos;
            v8s h8, l8;
#pragma unroll
            for (int c = 0; c < 8; ++c) {
                const float v = sp[c * 225];
                const unsigned short hb = bf16_rne(v);
                h8[c] = (short)hb;
                l8[c] = (short)bf16_rne(v - bf16_to_f(hb));
            }
            *(v8s*)(sh + pos * 32 + oct * 8) = h8;
            *(v8s*)(sl + pos * 32 + oct * 8) = l8;
        }
        __syncthreads();
#pragma unroll 1
        for (int k = 0; k < 9; ++k) {
            const int ky = k / 3, kx = k % 3;
            const int ip = (oy + ky) * 15 + (ox + kx);
            const v8s bh = *(const v8s*)(sh + ip * 32 + koff);
            const v8s bl = *(const v8s*)(sl + ip * 32 + koff);
            const int abase = (pass * 9 + k) * 256 + l;   // v8s units: ((pass*9+k)*4+i)*64 + l
#pragma unroll
            for (int i = 0; i < 4; ++i) {
                const v8s ah = WH[abase + i * 64];
                const v8s al = WL[abase + i * 64];
                acc[i] = __builtin_amdgcn_mfma_f32_16x16x32_bf16(ah, bh, acc[i], 0, 0, 0);
                acc[i] = __builtin_amdgcn_mfma_f32_16x16x32_bf16(ah, bl, acc[i], 0, 0, 0);
                acc[i] = __builtin_amdgcn_mfma_f32_16x16x32_bf16(al, bh, acc[i], 0, 0, 0);
            }
        }
    }
    // epilogue: C/D layout col=lane&15 (pos), row=(lane>>4)*4+reg (cout within tile)
    __syncthreads();
#pragma unroll
    for (int i = 0; i < 4; ++i)
#pragma unroll
        for (int r = 0; r < 4; ++r) {
            const int cout = i * 16 + (l >> 4) * 4 + r;
            scb[cout * 144 + p] = acc[i][r];
        }
    __syncthreads();
    for (int o = t; o < 2304; o += 576) {
        const int cout = o / 36, pp = o % 36;
        const int p00 = (pp / 6) * 24 + (pp % 6) * 2;   // (2*py)*12 + 2*px
        const float* cb = scb + cout * 144 + p00;
        float m = fmaxf(fmaxf(cb[0], cb[1]), fmaxf(cb[12], cb[13]));
        h2[(size_t)node * 2304 + o] = fmaxf(m, 0.f);
    }
}

// ---------------- conv3 (MFMA): Cin=64, Cout=128, 6x6 -> 4x4 -> relu+pool 2x2 ----------------
// 8 waves = 8 m-tiles (128 cout); single n-tile (16 conv positions); K=64 (2 ksteps) x 9 shifts.
__global__ __launch_bounds__(512, 2) void k_conv3(const float* __restrict__ h2, const float* __restrict__ agg,
                                                  const unsigned short* __restrict__ whi,
                                                  const unsigned short* __restrict__ wlo,
                                                  float* __restrict__ out) {
    const int node = blockIdx.x;
    const int t = threadIdx.x;
    __shared__ __align__(16) char smem[9216];
    unsigned short* sh = (unsigned short*)smem;           // hi: [36][64] bf16, 4608 B
    unsigned short* sl = (unsigned short*)(smem + 4608);  // lo
    float* scb = (float*)smem;                            // epilogue [128][16] f32 = 8192 B (reuse)

    const int l = t & 63;
    const int w = t >> 6;          // wave 0..7 = m-tile
    const int p = l & 15;          // conv position 0..15 (4x4)
    const int oy = p >> 2, ox = p & 3;
    const int koff = (l >> 4) * 8;

    const v4f vzero = {0.f, 0.f, 0.f, 0.f};
    v4f acc = vzero;

    const float* srcs0 = h2 + (size_t)node * 2304;
    const float* srcs1 = agg + (size_t)node * 2304;
    const v8s* WH = (const v8s*)whi;
    const v8s* WL = (const v8s*)wlo;

#pragma unroll 1
    for (int pass = 0; pass < 2; ++pass) {
        const float* S = pass ? srcs1 : srcs0;
        __syncthreads();
#pragma unroll 1
        for (int ii = t; ii < 288; ii += 512) {
            const int pos = ii % 36, oct = ii / 36;
            const float* sp = S + (oct * 8) * 36 + pos;
            v8s h8, l8;
#pragma unroll
            for (int c = 0; c < 8; ++c) {
                const float v = sp[c * 36];
                const unsigned short hb = bf16_rne(v);
                h8[c] = (short)hb;
                l8[c] = (short)bf16_rne(v - bf16_to_f(hb));
            }
            *(v8s*)(sh + pos * 64 + oct * 8) = h8;
            *(v8s*)(sl + pos * 64 + oct * 8) = l8;
        }
        __syncthreads();
#pragma unroll 1
        for (int k = 0; k < 9; ++k) {
            const int ky = k / 3, kx = k % 3;
            const int ip = (oy + ky) * 6 + (ox + kx);
#pragma unroll
            for (int ks = 0; ks < 2; ++ks) {
                const v8s bh = *(const v8s*)(sh + ip * 64 + ks * 32 + koff);
                const v8s bl = *(const v8s*)(sl + ip * 64 + ks * 32 + koff);
                const int ai = (((pass * 9 + k) * 2 + ks) * 8 + w) * 64 + l;
                const v8s ah = WH[ai];
                const v8s al = WL[ai];
                acc = __builtin_amdgcn_mfma_f32_16x16x32_bf16(ah, bh, acc, 0, 0, 0);
                acc = __builtin_amdgcn_mfma_f32_16x16x32_bf16(ah, bl, acc, 0, 0, 0);
                acc = __builtin_amdgcn_mfma_f32_16x16x32_bf16(al, bh, acc, 0, 0, 0);
            }
        }
    }
    __syncthreads();
#pragma unroll
    for (int r = 0; r < 4; ++r) {
        const int cout = w * 16 + (l >> 4) * 4 + r;
        scb[cout * 16 + p] = acc[r];
    }
    __syncthreads();
    {
        const int o = t;   // 512 outputs, 512 threads
        const int cout = o >> 2, pp = o & 3;
        const int p00 = (pp >> 1) * 8 + (pp & 1) * 2;   // (2*py)*4 + 2*px
        const float* cb = scb + cout * 16 + p00;
        float m = fmaxf(fmaxf(cb[0], cb[1]), fmaxf(cb[4], cb[5]));
        out[(size_t)node * 512 + o] = fmaxf(m, 0.f);
    }
}

// ---------------- launcher ----------------
extern "C" void kernel_launch(void* const* d_in, const int* in_sizes, int n_in,
                              void* d_out, int out_size, void* d_ws, size_t ws_size,
                              hipStream_t stream) {
    (void)in_sizes; (void)n_in; (void)out_size; (void)ws_size;
    const float* in_feat = (const float*)d_in[0];
    const float* w1s = (const float*)d_in[1];
    const float* w1n = (const float*)d_in[2];
    const float* w2s = (const float*)d_in[3];
    const float* w2n = (const float*)d_in[4];
    const float* w3s = (const float*)d_in[5];
    const float* w3n = (const float*)d_in[6];
    const int* srcp = (const int*)d_in[7];
    const int* dstp = (const int*)d_in[8];
    float* outp = (float*)d_out;

    char* w = (char*)d_ws;
    size_t off = 0;
    auto alloc = [&](size_t bytes) { void* p = w + off; off += (bytes + 255) & ~(size_t)255; return p; };
    int* cnt    = (int*)alloc(N_NODES * sizeof(int));
    int* rowptr = (int*)alloc((N_NODES + 1) * sizeof(int));
    int* fill   = (int*)alloc(N_NODES * sizeof(int));
    int* col    = (int*)alloc(N_EDGES * sizeof(int));
    unsigned short* w2hi = (unsigned short*)alloc(36864 * sizeof(unsigned short));
    unsigned short* w2lo = (unsigned short*)alloc(36864 * sizeof(unsigned short));
    unsigned short* w3hi = (unsigned short*)alloc(147456 * sizeof(unsigned short));
    unsigned short* w3lo = (unsigned short*)alloc(147456 * sizeof(unsigned short));
    float* agg1 = (float*)alloc((size_t)N_NODES * 1024 * sizeof(float));
    float* h1   = (float*)alloc((size_t)N_NODES * 7200 * sizeof(float));
    float* agg2 = (float*)alloc((size_t)N_NODES * 7200 * sizeof(float));
    float* h2   = (float*)alloc((size_t)N_NODES * 2304 * sizeof(float));
    float* agg3 = (float*)alloc((size_t)N_NODES * 2304 * sizeof(float));

    hipMemsetAsync(cnt, 0, N_NODES * sizeof(int), stream);
    hipMemsetAsync(fill, 0, N_NODES * sizeof(int), stream);

    k_hist<<<(N_EDGES + 255) / 256, 256, 0, stream>>>(dstp, cnt);
    k_scan<<<1, 1024, 0, stream>>>(cnt, rowptr);
    k_scatter<<<(N_EDGES + 255) / 256, 256, 0, stream>>>(srcp, dstp, rowptr, fill, col);
    k_pack2<<<144, 256, 0, stream>>>(w2s, w2n, w2hi, w2lo);
    k_pack3<<<576, 256, 0, stream>>>(w3s, w3n, w3hi, w3lo);

    // layer 1
    k_agg<1024><<<N_NODES, 256, 0, stream>>>(in_feat, rowptr, col, agg1);
    k_conv1<<<N_NODES, 256, 0, stream>>>(in_feat, agg1, w1s, w1n, h1);
    // layer 2 (MFMA)
    k_agg<7200><<<N_NODES, 256, 0, stream>>>(h1, rowptr, col, agg2);
    k_conv2<<<N_NODES, 576, 0, stream>>>(h1, agg2, w2hi, w2lo, h2);
    // layer 3 (MFMA)
    k_agg<2304><<<N_NODES, 256, 0, stream>>>(h2, rowptr, col, agg3);
    k_conv3<<<N_NODES, 512, 0, stream>>>(h2, agg3, w3hi, w3lo, outp);
}

// Round 11
// 398.064 us; speedup vs baseline: 2.0610x; 1.1329x over previous
//
#include <hip/hip_runtime.h>
#include <hip/hip_bf16.h>

#define N_NODES 2000
#define N_EDGES 32000

typedef __attribute__((ext_vector_type(8))) short v8s;
typedef __attribute__((ext_vector_type(4))) float v4f;

__device__ __forceinline__ unsigned short bf16_rne(float x) {
    unsigned u = __float_as_uint(x);
    unsigned r = (u + 0x7fffu + ((u >> 16) & 1u)) >> 16;
    return (unsigned short)r;
}
__device__ __forceinline__ float bf16_to_f(unsigned short h) {
    return __uint_as_float(((unsigned)h) << 16);
}

// ---------------- CSR build ----------------
__global__ __launch_bounds__(256) void k_hist(const int* __restrict__ dst, int* __restrict__ cnt) {
    int e = blockIdx.x * 256 + threadIdx.x;
    if (e < N_EDGES) atomicAdd(&cnt[dst[e]], 1);
}

__global__ __launch_bounds__(1024) void k_scan(const int* __restrict__ cnt, int* __restrict__ rowptr) {
    __shared__ int buf[2][2048];
    const int t = threadIdx.x;
    for (int i = t; i < 2048; i += 1024) buf[0][i] = (i < N_NODES) ? cnt[i] : 0;
    __syncthreads();
    int cur = 0;
    for (int off = 1; off < 2048; off <<= 1) {
        for (int i = t; i < 2048; i += 1024) {
            int v = buf[cur][i];
            if (i >= off) v += buf[cur][i - off];
            buf[cur ^ 1][i] = v;
        }
        __syncthreads();
        cur ^= 1;
    }
    for (int i = t; i < N_NODES; i += 1024) rowptr[i + 1] = buf[cur][i];
    if (t == 0) rowptr[0] = 0;
}

__global__ __launch_bounds__(256) void k_scatter(const int* __restrict__ src, const int* __restrict__ dst,
                                                 const int* __restrict__ rowptr, int* __restrict__ fill,
                                                 int* __restrict__ col) {
    int e = blockIdx.x * 256 + threadIdx.x;
    if (e < N_EDGES) {
        int d = dst[e];
        int pos = atomicAdd(&fill[d], 1);
        col[rowptr[d] + pos] = src[e];
    }
}

// ---------------- weight split+pack for MFMA fragments ----------------
__global__ __launch_bounds__(256) void k_pack2(const float* __restrict__ ws, const float* __restrict__ wn,
                                               unsigned short* __restrict__ whi, unsigned short* __restrict__ wlo) {
    int x = blockIdx.x * 256 + threadIdx.x;
    if (x >= 36864) return;
    int j = x & 7, l = (x >> 3) & 63, i = (x >> 9) & 3, k = (x >> 11) % 9, s = x / 18432;
    int cout = i * 16 + (l & 15), cin = (l >> 4) * 8 + j;
    float w = (s ? wn : ws)[(cout * 32 + cin) * 9 + k];
    unsigned short h = bf16_rne(w);
    whi[x] = h;
    wlo[x] = bf16_rne(w - bf16_to_f(h));
}

__global__ __launch_bounds__(256) void k_pack3(const float* __restrict__ ws, const float* __restrict__ wn,
                                               unsigned short* __restrict__ whi, unsigned short* __restrict__ wlo) {
    int x = blockIdx.x * 256 + threadIdx.x;
    if (x >= 147456) return;
    int j = x & 7, l = (x >> 3) & 63, i = (x >> 9) & 7, ks = (x >> 12) & 1, k = (x >> 13) % 9, s = x / 73728;
    int cout = i * 16 + (l & 15), cin = ks * 32 + (l >> 4) * 8 + j;
    float w = (s ? wn : ws)[(cout * 64 + cin) * 9 + k];
    unsigned short h = bf16_rne(w);
    whi[x] = h;
    wlo[x] = bf16_rne(w - bf16_to_f(h));
}

// ---------------- window-major mean aggregation ----------------
// One wave per (node, feature-window). Grid = win*N_NODES + node so all nodes
// process the same ~1-2 MB window concurrently -> gathers hit per-XCD L2.
template <int F4, int NWIN>
__global__ __launch_bounds__(64) void k_aggw(const float* __restrict__ feat, const int* __restrict__ rowptr,
                                             const int* __restrict__ col, float* __restrict__ out) {
    constexpr int WIN4 = F4 / NWIN;   // float4 slots per window (<= 64)
    const int node = blockIdx.x % N_NODES;
    const int win = blockIdx.x / N_NODES;
    const int t = threadIdx.x;
    const int beg = rowptr[node], end = rowptr[node + 1];
    const int deg = end - beg;
    const float inv = 1.0f / (float)(deg > 1 ? deg : 1);
    __shared__ int nb[64];
    const int f4 = win * WIN4 + t;
    const bool act = (t < WIN4);
    const float4* F = (const float4*)feat;
    float4 a0 = {0.f, 0.f, 0.f, 0.f}, a1 = {0.f, 0.f, 0.f, 0.f};
    for (int jb = beg; jb < end; jb += 64) {
        const int cnt = min(end - jb, 64);
        __syncthreads();
        if (t < cnt) nb[t] = col[jb + t];
        __syncthreads();
        if (act) {
            int j = 0;
            for (; j + 1 < cnt; j += 2) {
                const float4 v0 = F[(size_t)nb[j] * F4 + f4];
                const float4 v1 = F[(size_t)nb[j + 1] * F4 + f4];
                a0.x += v0.x; a0.y += v0.y; a0.z += v0.z; a0.w += v0.w;
                a1.x += v1.x; a1.y += v1.y; a1.z += v1.z; a1.w += v1.w;
            }
            if (j < cnt) {
                const float4 v0 = F[(size_t)nb[j] * F4 + f4];
                a0.x += v0.x; a0.y += v0.y; a0.z += v0.z; a0.w += v0.w;
            }
        }
    }
    if (act) {
        float4 r = {(a0.x + a1.x) * inv, (a0.y + a1.y) * inv, (a0.z + a1.z) * inv, (a0.w + a1.w) * inv};
        *reinterpret_cast<float4*>(out + ((size_t)node * F4 + f4) * 4) = r;
    }
}

// ---------------- conv1: Cin=1, Cout=32 (VALU path, small FLOPs) ----------------
__global__ __launch_bounds__(256) void k_conv1(const float* __restrict__ x, const float* __restrict__ xagg,
                                               const float* __restrict__ w1s, const float* __restrict__ w1n,
                                               float* __restrict__ h1) {
    const int node = blockIdx.x;
    const int t = threadIdx.x;
    __shared__ __align__(16) float xs[1024];
    __shared__ __align__(16) float xa[1024];
    __shared__ __align__(16) float wl[9 * 2 * 32];
    {
        const float4* xsrc = reinterpret_cast<const float4*>(x + (size_t)node * 1024);
        const float4* asrc = reinterpret_cast<const float4*>(xagg + (size_t)node * 1024);
        reinterpret_cast<float4*>(xs)[t] = xsrc[t];
        reinterpret_cast<float4*>(xa)[t] = asrc[t];
        for (int i = t; i < 576; i += 256) {
            int s = i / 288, rem = i % 288;
            int c = rem / 9, k = rem % 9;
            wl[(k * 2 + s) * 32 + c] = (s ? w1n : w1s)[rem];
        }
    }
    __syncthreads();
    const int g = t >> 5;
    const int p = t & 31;
    for (int r = p; r < 225; r += 32) {
        const int py = r / 15, px = r % 15;
        const int oy = 2 * py, ox = 2 * px;
        float acc[4][4];
#pragma unroll
        for (int d = 0; d < 4; ++d)
#pragma unroll
            for (int j = 0; j < 4; ++j) acc[d][j] = 0.f;
#pragma unroll
        for (int ky = 0; ky < 3; ++ky)
#pragma unroll
            for (int kx = 0; kx < 3; ++kx) {
                const int k = ky * 3 + kx;
                const float xv[4] = {xs[(oy + ky) * 32 + ox + kx],     xs[(oy + ky) * 32 + ox + kx + 1],
                                     xs[(oy + ky + 1) * 32 + ox + kx], xs[(oy + ky + 1) * 32 + ox + kx + 1]};
                const float av[4] = {xa[(oy + ky) * 32 + ox + kx],     xa[(oy + ky) * 32 + ox + kx + 1],
                                     xa[(oy + ky + 1) * 32 + ox + kx], xa[(oy + ky + 1) * 32 + ox + kx + 1]};
                const float4 wS = *reinterpret_cast<const float4*>(&wl[(k * 2 + 0) * 32 + g * 4]);
                const float4 wN = *reinterpret_cast<const float4*>(&wl[(k * 2 + 1) * 32 + g * 4]);
                const float wSa[4] = {wS.x, wS.y, wS.z, wS.w};
                const float wNa[4] = {wN.x, wN.y, wN.z, wN.w};
#pragma unroll
                for (int d = 0; d < 4; ++d)
#pragma unroll
                    for (int j = 0; j < 4; ++j) acc[d][j] += xv[d] * wSa[j] + av[d] * wNa[j];
            }
#pragma unroll
        for (int j = 0; j < 4; ++j) {
            float m = fmaxf(fmaxf(acc[0][j], acc[1][j]), fmaxf(acc[2][j], acc[3][j]));
            m = fmaxf(m, 0.f);
            h1[(size_t)node * 7200 + (size_t)(g * 4 + j) * 225 + r] = m;
        }
    }
}

// ---------------- conv2 (MFMA): Cin=32, Cout=64, 15x15 -> 13x13 -> relu+pool 6x6 ----------------
__global__ __launch_bounds__(576, 2) void k_conv2(const float* __restrict__ h1, const float* __restrict__ agg,
                                                  const unsigned short* __restrict__ whi,
                                                  const unsigned short* __restrict__ wlo,
                                                  float* __restrict__ h2) {
    const int node = blockIdx.x;
    const int t = threadIdx.x;
    __shared__ __align__(16) char smem[36864];
    unsigned short* sh = (unsigned short*)smem;            // hi: [225][32] bf16
    unsigned short* sl = (unsigned short*)(smem + 14400);  // lo
    float* scb = (float*)smem;                             // epilogue C-buffer [64][144] (reuse)

    const int l = t & 63;
    const int w = t >> 6;             // wave 0..8 = n-tile
    const int p = w * 16 + (l & 15);  // conv position 0..143 on 12x12 grid
    const int oy = p / 12, ox = p % 12;
    const int koff = (l >> 4) * 8;

    const v4f vzero = {0.f, 0.f, 0.f, 0.f};
    v4f acc[4] = {vzero, vzero, vzero, vzero};

    const float* srcs0 = h1 + (size_t)node * 7200;
    const float* srcs1 = agg + (size_t)node * 7200;
    const v8s* WH = (const v8s*)whi;
    const v8s* WL = (const v8s*)wlo;

#pragma unroll 1
    for (int pass = 0; pass < 2; ++pass) {
        const float* S = pass ? srcs1 : srcs0;
        __syncthreads();
#pragma unroll 1
        for (int ii = t; ii < 900; ii += 576) {
            const int pos = ii % 225, oct = ii / 225;
            const float* sp = S + (oct * 8) * 225 + pos;
            v8s h8, l8;
#pragma unroll
            for (int c = 0; c < 8; ++c) {
                const float v = sp[c * 225];
                const unsigned short hb = bf16_rne(v);
                h8[c] = (short)hb;
                l8[c] = (short)bf16_rne(v - bf16_to_f(hb));
            }
            *(v8s*)(sh + pos * 32 + oct * 8) = h8;
            *(v8s*)(sl + pos * 32 + oct * 8) = l8;
        }
        __syncthreads();
#pragma unroll 1
        for (int k = 0; k < 9; ++k) {
            const int ky = k / 3, kx = k % 3;
            const int ip = (oy + ky) * 15 + (ox + kx);
            const v8s bh = *(const v8s*)(sh + ip * 32 + koff);
            const v8s bl = *(const v8s*)(sl + ip * 32 + koff);
            const int abase = (pass * 9 + k) * 256 + l;
#pragma unroll
            for (int i = 0; i < 4; ++i) {
                const v8s ah = WH[abase + i * 64];
                const v8s al = WL[abase + i * 64];
                acc[i] = __builtin_amdgcn_mfma_f32_16x16x32_bf16(ah, bh, acc[i], 0, 0, 0);
                acc[i] = __builtin_amdgcn_mfma_f32_16x16x32_bf16(ah, bl, acc[i], 0, 0, 0);
                acc[i] = __builtin_amdgcn_mfma_f32_16x16x32_bf16(al, bh, acc[i], 0, 0, 0);
            }
        }
    }
    __syncthreads();
#pragma unroll
    for (int i = 0; i < 4; ++i)
#pragma unroll
        for (int r = 0; r < 4; ++r) {
            const int cout = i * 16 + (l >> 4) * 4 + r;
            scb[cout * 144 + p] = acc[i][r];
        }
    __syncthreads();
    for (int o = t; o < 2304; o += 576) {
        const int cout = o / 36, pp = o % 36;
        const int p00 = (pp / 6) * 24 + (pp % 6) * 2;
        const float* cb = scb + cout * 144 + p00;
        float m = fmaxf(fmaxf(cb[0], cb[1]), fmaxf(cb[12], cb[13]));
        h2[(size_t)node * 2304 + o] = fmaxf(m, 0.f);
    }
}

// ---------------- conv3 (MFMA): Cin=64, Cout=128, 6x6 -> 4x4 -> relu+pool 2x2 ----------------
__global__ __launch_bounds__(512, 2) void k_conv3(const float* __restrict__ h2, const float* __restrict__ agg,
                                                  const unsigned short* __restrict__ whi,
                                                  const unsigned short* __restrict__ wlo,
                                                  float* __restrict__ out) {
    const int node = blockIdx.x;
    const int t = threadIdx.x;
    __shared__ __align__(16) char smem[9216];
    unsigned short* sh = (unsigned short*)smem;           // hi: [36][64] bf16
    unsigned short* sl = (unsigned short*)(smem + 4608);  // lo
    float* scb = (float*)smem;                            // epilogue [128][16] (reuse)

    const int l = t & 63;
    const int w = t >> 6;          // wave 0..7 = m-tile
    const int p = l & 15;          // conv position (4x4)
    const int oy = p >> 2, ox = p & 3;
    const int koff = (l >> 4) * 8;

    const v4f vzero = {0.f, 0.f, 0.f, 0.f};
    v4f acc = vzero;

    const float* srcs0 = h2 + (size_t)node * 2304;
    const float* srcs1 = agg + (size_t)node * 2304;
    const v8s* WH = (const v8s*)whi;
    const v8s* WL = (const v8s*)wlo;

#pragma unroll 1
    for (int pass = 0; pass < 2; ++pass) {
        const float* S = pass ? srcs1 : srcs0;
        __syncthreads();
#pragma unroll 1
        for (int ii = t; ii < 288; ii += 512) {
            const int pos = ii % 36, oct = ii / 36;
            const float* sp = S + (oct * 8) * 36 + pos;
            v8s h8, l8;
#pragma unroll
            for (int c = 0; c < 8; ++c) {
                const float v = sp[c * 36];
                const unsigned short hb = bf16_rne(v);
                h8[c] = (short)hb;
                l8[c] = (short)bf16_rne(v - bf16_to_f(hb));
            }
            *(v8s*)(sh + pos * 64 + oct * 8) = h8;
            *(v8s*)(sl + pos * 64 + oct * 8) = l8;
        }
        __syncthreads();
#pragma unroll 1
        for (int k = 0; k < 9; ++k) {
            const int ky = k / 3, kx = k % 3;
            const int ip = (oy + ky) * 6 + (ox + kx);
#pragma unroll
            for (int ks = 0; ks < 2; ++ks) {
                const v8s bh = *(const v8s*)(sh + ip * 64 + ks * 32 + koff);
                const v8s bl = *(const v8s*)(sl + ip * 64 + ks * 32 + koff);
                const int ai = (((pass * 9 + k) * 2 + ks) * 8 + w) * 64 + l;
                const v8s ah = WH[ai];
                const v8s al = WL[ai];
                acc = __builtin_amdgcn_mfma_f32_16x16x32_bf16(ah, bh, acc, 0, 0, 0);
                acc = __builtin_amdgcn_mfma_f32_16x16x32_bf16(ah, bl, acc, 0, 0, 0);
                acc = __builtin_amdgcn_mfma_f32_16x16x32_bf16(al, bh, acc, 0, 0, 0);
            }
        }
    }
    __syncthreads();
#pragma unroll
    for (int r = 0; r < 4; ++r) {
        const int cout = w * 16 + (l >> 4) * 4 + r;
        scb[cout * 16 + p] = acc[r];
    }
    __syncthreads();
    {
        const int o = t;
        const int cout = o >> 2, pp = o & 3;
        const int p00 = (pp >> 1) * 8 + (pp & 1) * 2;
        const float* cb = scb + cout * 16 + p00;
        float m = fmaxf(fmaxf(cb[0], cb[1]), fmaxf(cb[4], cb[5]));
        out[(size_t)node * 512 + o] = fmaxf(m, 0.f);
    }
}

// ---------------- launcher ----------------
extern "C" void kernel_launch(void* const* d_in, const int* in_sizes, int n_in,
                              void* d_out, int out_size, void* d_ws, size_t ws_size,
                              hipStream_t stream) {
    (void)in_sizes; (void)n_in; (void)out_size; (void)ws_size;
    const float* in_feat = (const float*)d_in[0];
    const float* w1s = (const float*)d_in[1];
    const float* w1n = (const float*)d_in[2];
    const float* w2s = (const float*)d_in[3];
    const float* w2n = (const float*)d_in[4];
    const float* w3s = (const float*)d_in[5];
    const float* w3n = (const float*)d_in[6];
    const int* srcp = (const int*)d_in[7];
    const int* dstp = (const int*)d_in[8];
    float* outp = (float*)d_out;

    char* w = (char*)d_ws;
    size_t off = 0;
    auto alloc = [&](size_t bytes) { void* p = w + off; off += (bytes + 255) & ~(size_t)255; return p; };
    int* cnt    = (int*)alloc(N_NODES * sizeof(int));
    int* rowptr = (int*)alloc((N_NODES + 1) * sizeof(int));
    int* fill   = (int*)alloc(N_NODES * sizeof(int));
    int* col    = (int*)alloc(N_EDGES * sizeof(int));
    unsigned short* w2hi = (unsigned short*)alloc(36864 * sizeof(unsigned short));
    unsigned short* w2lo = (unsigned short*)alloc(36864 * sizeof(unsigned short));
    unsigned short* w3hi = (unsigned short*)alloc(147456 * sizeof(unsigned short));
    unsigned short* w3lo = (unsigned short*)alloc(147456 * sizeof(unsigned short));
    float* agg1 = (float*)alloc((size_t)N_NODES * 1024 * sizeof(float));
    float* h1   = (float*)alloc((size_t)N_NODES * 7200 * sizeof(float));
    float* agg2 = (float*)alloc((size_t)N_NODES * 7200 * sizeof(float));
    float* h2   = (float*)alloc((size_t)N_NODES * 2304 * sizeof(float));
    float* agg3 = (float*)alloc((size_t)N_NODES * 2304 * sizeof(float));

    hipMemsetAsync(cnt, 0, N_NODES * sizeof(int), stream);
    hipMemsetAsync(fill, 0, N_NODES * sizeof(int), stream);

    k_hist<<<(N_EDGES + 255) / 256, 256, 0, stream>>>(dstp, cnt);
    k_scan<<<1, 1024, 0, stream>>>(cnt, rowptr);
    k_scatter<<<(N_EDGES + 255) / 256, 256, 0, stream>>>(srcp, dstp, rowptr, fill, col);
    k_pack2<<<144, 256, 0, stream>>>(w2s, w2n, w2hi, w2lo);
    k_pack3<<<576, 256, 0, stream>>>(w3s, w3n, w3hi, w3lo);

    // layer 1: F=1024 -> F4=256, 4 windows of 64 float4 (1 KB, 2 MB/window)
    k_aggw<256, 4><<<4 * N_NODES, 64, 0, stream>>>(in_feat, rowptr, col, agg1);
    k_conv1<<<N_NODES, 256, 0, stream>>>(in_feat, agg1, w1s, w1n, h1);
    // layer 2: F=7200 -> F4=1800, 30 windows of 60 float4 (0.94 KB, 1.9 MB/window)
    k_aggw<1800, 30><<<30 * N_NODES, 64, 0, stream>>>(h1, rowptr, col, agg2);
    k_conv2<<<N_NODES, 576, 0, stream>>>(h1, agg2, w2hi, w2lo, h2);
    // layer 3: F=2304 -> F4=576, 9 windows of 64 float4 (1 KB, 2 MB/window)
    k_aggw<576, 9><<<9 * N_NODES, 64, 0, stream>>>(h2, rowptr, col, agg3);
    k_conv3<<<N_NODES, 512, 0, stream>>>(h2, agg3, w3hi, w3lo, outp);
}